// Round 5
// baseline (2181.036 us; speedup 1.0000x reference)
//
#include <hip/hip_runtime.h>

// ---------- helpers ----------
typedef __bf16 bf16x8 __attribute__((ext_vector_type(8)));
typedef float f32x4 __attribute__((ext_vector_type(4)));

__device__ __forceinline__ float bf2f(unsigned short u) {
  union { unsigned int i; float f; } x;
  x.i = ((unsigned int)u) << 16;
  return x.f;
}
__device__ __forceinline__ unsigned short f2bf(float f) {
  union { float f; unsigned int i; } x;
  x.f = f;
  unsigned int u = x.i;
  u += 0x7fffu + ((u >> 16) & 1u);  // RNE
  return (unsigned short)(u >> 16);
}
__device__ __forceinline__ unsigned int fbits(float f) {
  union { float f; unsigned int i; } x; x.f = f; return x.i;
}
// pack two fp32 -> two truncated bf16 in ONE v_perm_b32
__device__ __forceinline__ unsigned int pack_bf16_trunc(float lo, float hi) {
  return __builtin_amdgcn_perm(fbits(hi), fbits(lo), 0x07060302u);
}

// async global->LDS, 16B per lane, LDS dest wave-uniform base (lane auto-offsets by 16B)
__device__ __forceinline__ void load16_to_lds(const void* g, void* l) {
  __builtin_amdgcn_global_load_lds(
      (__attribute__((address_space(1))) void*)const_cast<void*>(g),
      (__attribute__((address_space(3))) void*)l, 16, 0, 0);
}

// packed lower-triangle score buffer: 528 blocks of 128x128 bf16, block-linear.
// block (by,bx), bx<=by, stored at (by*(by+1)/2 + bx)*16384; elem (r,c) at +r*128+c.
#define TRI_BLK 16384
#define TRI_NBLK 528
#define PER_BATCH_EL (TRI_NBLK * TRI_BLK)  // 8,650,752 el = 17.3 MB

// ---------- cast fp32 -> bf16 (RNE, vectorized x4) ----------
__global__ __launch_bounds__(256) void cast_f32_to_bf16(const float* __restrict__ src,
                                                        unsigned short* __restrict__ dst,
                                                        int n4) {
  int i = blockIdx.x * 256 + threadIdx.x;
  if (i < n4) {
    float4 f = ((const float4*)src)[i];
    ushort4 o;
    o.x = f2bf(f.x); o.y = f2bf(f.y); o.z = f2bf(f.z); o.w = f2bf(f.w);
    ((ushort4*)dst)[i] = o;
  }
}

// ---------- 256x256 8-phase NT GEMM, BK=32, 2 blocks/CU ----------
// C[m][n] = sum_k A[m][k]*B[n][k]. 8 waves (2M x 4N), 512 threads, 64 KiB LDS
// (2 bufs x 32 KiB) -> TWO blocks co-resident per CU: the second block's waves
// hide the first's barrier/vmcnt stalls and smooth integer-round raggedness
// (544-block scores grid: 3 hard rounds -> ~2.2 fluid rounds).
// LDS per buffer: elem = buf*16384 + ab*8192 + h*4096 + r*32 + c  (bf16)
// st_16x32 swizzle on BOTH pre-swizzled global source (linear gload_lds dest)
// and ds_read: col ^= 16 when (r&8).
// Per iteration (2 k-tiles of 32): 8 phases, 1 stage-op per phase; counted
// s_waitcnt vmcnt(2) at phases 4/8 (ledger: 6 outstanding -> drain tile t+1's 4).
// MODE 0: proj   -> bf16 C row-major, grid (N/256, M/256, z)
// MODE 1: scores -> bf16*scale into PACKED-TRI (128-blocks), grid (136, 1, nb)
template <int MODE>
__global__ __launch_bounds__(512, 4) void gemm8(const unsigned short* __restrict__ A, int lda,
                                                const unsigned short* __restrict__ B, int ldb,
                                                void* __restrict__ Cv, int ldc, int K, float scale,
                                                long long sA, long long sB, long long sC) {
  int by, bx;
  if constexpr (MODE == 1) {
    int b = blockIdx.x;
    by = (int)((__fsqrt_rn(8.f * b + 1.f) - 1.f) * 0.5f);
    while ((by + 1) * (by + 2) / 2 <= b) ++by;
    while (by * (by + 1) / 2 > b) --by;
    bx = b - by * (by + 1) / 2;
  } else {
    by = blockIdx.y;
    bx = blockIdx.x;
  }
  A += (long long)blockIdx.z * sA;
  B += (long long)blockIdx.z * sB;

  const int rowBase = by * 256;
  const int colBase = bx * 256;

  __shared__ unsigned short lds[32768];  // 64 KiB

  const int tid = threadIdx.x;
  const int wave = tid >> 6;
  const int lane = tid & 63;
  const int wr = wave >> 2;  // 0..1  (M half)
  const int wc = wave & 3;   // 0..3  (N quarter)

  // ---- staging source precompute (pre-swizzled global addresses) ----
  const int rS = tid >> 2;                            // 0..127: row within half-tile
  const int ceS = ((tid & 3) * 8) ^ ((rS & 8) << 1);  // swizzled k-el offset in 32-chunk
  const unsigned short* sAp[2];
  const unsigned short* sBp[2];
#pragma unroll
  for (int h = 0; h < 2; ++h) {
    sAp[h] = A + (size_t)(rowBase + h * 128 + rS) * lda + ceS;
    sBp[h] = B + (size_t)(colBase + h * 128 + rS) * ldb + ceS;
  }
  const int nT = K >> 5;  // 32-el k-tiles
  const int nIter = nT >> 1;

  // ---- LDS read bases (swizzled) ----
  const int laneRow = lane & 15;
  const int csw = ((lane >> 4) * 8) ^ ((laneRow & 8) << 1);
  const int aBase = wr * 4096 + laneRow * 32 + csw;
  const int bBase = 8192 + (wc >> 1) * 4096 + ((wc & 1) * 64 + laneRow) * 32 + csw;

  f32x4 acc[8][4];
#pragma unroll
  for (int i = 0; i < 8; ++i)
#pragma unroll
    for (int j = 0; j < 4; ++j) {
      f32x4 z = {0.f, 0.f, 0.f, 0.f};
      acc[i][j] = z;
    }
  bf16x8 af[4];     // current qm: 4 M-frags
  bf16x8 bq[2][2];  // both qn: [qn][j]

  auto STAGE_A = [&](int h, int tau, int bufsel) {
    if (tau < nT) {
      unsigned short* d = &lds[bufsel * 16384 + h * 4096 + wave * 512];
      load16_to_lds(sAp[h] + tau * 32, d);
    }
  };
  auto STAGE_B = [&](int h, int tau, int bufsel) {
    if (tau < nT) {
      unsigned short* d = &lds[bufsel * 16384 + 8192 + h * 4096 + wave * 512];
      load16_to_lds(sBp[h] + tau * 32, d);
    }
  };

#define LOAD_A(qm, CO)                                                                   \
  _Pragma("unroll") for (int i_ = 0; i_ < 4; ++i_)                                       \
      af[i_] = *(const bf16x8*)&lds[(CO) + aBase + ((qm)*4 + i_) * 512];

#define LOAD_B(qn, CO)                                                                   \
  _Pragma("unroll") for (int j_ = 0; j_ < 2; ++j_)                                       \
      bq[qn][j_] = *(const bf16x8*)&lds[(CO) + bBase + ((qn)*2 + j_) * 512];

#define MFMA_Q(qm, qn)                                                                   \
  {                                                                                      \
    __builtin_amdgcn_s_setprio(1);                                                       \
    _Pragma("unroll") for (int i_ = 0; i_ < 4; ++i_)                                     \
    _Pragma("unroll") for (int j_ = 0; j_ < 2; ++j_)                                     \
        acc[(qm)*4 + i_][(qn)*2 + j_] = __builtin_amdgcn_mfma_f32_16x16x32_bf16(         \
            bq[qn][j_], af[i_], acc[(qm)*4 + i_][(qn)*2 + j_], 0, 0, 0);                 \
    __builtin_amdgcn_s_setprio(0);                                                       \
  }

#define BAR() __builtin_amdgcn_s_barrier()
#define WLG0()                                             \
  {                                                        \
    asm volatile("s_waitcnt lgkmcnt(0)" ::: "memory");     \
    __builtin_amdgcn_sched_barrier(0);                     \
  }

  // ---- prologue: A(0),B(0) -> buf0 [4 ops]; B(1) -> buf1 [2 ops] ----
  STAGE_A(0, 0, 0);
  STAGE_A(1, 0, 0);
  STAGE_B(0, 0, 0);
  STAGE_B(1, 0, 0);
  STAGE_B(0, 1, 1);
  STAGE_B(1, 1, 1);
  asm volatile("s_waitcnt vmcnt(2)" ::: "memory");  // tile 0 landed; B(1) may fly
  BAR();

  for (int it = 0; it < nIter; ++it) {
    const int ta = 2 * it + 1, tb = 2 * it + 2, tc = 2 * it + 3;
    const bool sb = tb < nT, sc = tc < nT;

    // ---- phase 1: tile t0 (buf0), quadrant (0,0) ----
    LOAD_A(0, 0);
    LOAD_B(0, 0);
    STAGE_A(0, ta, 1);
    BAR();
    WLG0();
    MFMA_Q(0, 0);
    BAR();
    // ---- phase 2: (0,1) ----
    LOAD_B(1, 0);
    STAGE_A(1, ta, 1);
    BAR();
    WLG0();
    MFMA_Q(0, 1);
    BAR();
    // ---- phase 3: (1,0) ----
    LOAD_A(1, 0);
    STAGE_B(0, tb, 0);
    BAR();
    WLG0();
    MFMA_Q(1, 0);
    BAR();
    // ---- phase 4: (1,1) + vmcnt ----
    STAGE_B(1, tb, 0);
    if (sb) { asm volatile("s_waitcnt vmcnt(2)" ::: "memory"); }
    else    { asm volatile("s_waitcnt vmcnt(0)" ::: "memory"); }
    BAR();
    MFMA_Q(1, 1);
    BAR();
    // ---- phase 5: tile t1 (buf1), quadrant (0,0) ----
    LOAD_A(0, 16384);
    LOAD_B(0, 16384);
    STAGE_A(0, tb, 0);
    BAR();
    WLG0();
    MFMA_Q(0, 0);
    BAR();
    // ---- phase 6: (0,1) ----
    LOAD_B(1, 16384);
    STAGE_A(1, tb, 0);
    BAR();
    WLG0();
    MFMA_Q(0, 1);
    BAR();
    // ---- phase 7: (1,0) ----
    LOAD_A(1, 16384);
    STAGE_B(0, tc, 1);
    BAR();
    WLG0();
    MFMA_Q(1, 0);
    BAR();
    // ---- phase 8: (1,1) + vmcnt ----
    STAGE_B(1, tc, 1);
    if (sc) { asm volatile("s_waitcnt vmcnt(2)" ::: "memory"); }
    else    { asm volatile("s_waitcnt vmcnt(0)" ::: "memory"); }
    BAR();
    MFMA_Q(1, 1);
    BAR();
  }

  // ---- epilogue: lane holds C[row=16fi+er][cols=16fj+ec..+3] per frag ----
  const int er = lane & 15;
  const int ec = (lane >> 4) * 4;
  if constexpr (MODE == 1) {
    const int rbB = 2 * by + wr;
    const int cbB = 2 * bx + (wc >> 1);
    if (cbB <= rbB) {  // skip upper quadrant of diagonal 256-tiles (not stored)
      unsigned short* C = (unsigned short*)Cv + (long long)blockIdx.z * sC +
                          (size_t)(rbB * (rbB + 1) / 2 + cbB) * TRI_BLK;
#pragma unroll
      for (int fi = 0; fi < 8; ++fi)
#pragma unroll
        for (int fj = 0; fj < 4; ++fj) {
          f32x4 a = acc[fi][fj];
          a[0] *= scale; a[1] *= scale; a[2] *= scale; a[3] *= scale;
          uint2 p;
          p.x = pack_bf16_trunc(a[0], a[1]);
          p.y = pack_bf16_trunc(a[2], a[3]);
          int row = fi * 16 + er;
          int col = (wc & 1) * 64 + fj * 16 + ec;
          *(uint2*)(C + row * 128 + col) = p;
        }
    }
  } else {
    unsigned short* C = (unsigned short*)Cv + (long long)blockIdx.z * sC;
#pragma unroll
    for (int fi = 0; fi < 8; ++fi)
#pragma unroll
      for (int fj = 0; fj < 4; ++fj) {
        uint2 p;
        p.x = pack_bf16_trunc(acc[fi][fj][0], acc[fi][fj][1]);
        p.y = pack_bf16_trunc(acc[fi][fj][2], acc[fi][fj][3]);
        size_t base = (size_t)(rowBase + wr * 128 + fi * 16 + er) * ldc +
                      (size_t)(colBase + wc * 64 + fj * 16 + ec);
        *(uint2*)(C + base) = p;
      }
  }
#undef LOAD_A
#undef LOAD_B
#undef MFMA_Q
#undef BAR
#undef WLG0
}

// ---------- PV: paired 128x256 tiles, 3-buffer deep pipeline ----------
// One block = TWO row-blocks (byDeep=31-p, byShallow=p): depth sum
// 2(32-p)+2(p+1) = 66 k-tiles CONSTANT -> perfect balance, 256 equal blocks.
// Per segment: C[128r][256c] = sum_k P[r][k]*Vt[c][k]; P packed-tri row-block by,
// K = 128*(by+1) (diag upper-tri zeros from softmax). 8 waves (2Mx4N), 64x64/wave.
// LDS 3 bufs x 24576 el (144 KiB): {A[2kh][128r][32c] | B[2h][2kh][128r][32c]},
// st_16x32 swizzle both sides. Pipeline depth 2 tiles: compute t (buf t%3),
// t+1 landed, t+2 issuing. Ledger: prologue 12 ops, vmcnt(6) => t0 landed;
// per tile P1 +2 (A(t+2)), P2 +4 (B(t+2)), vmcnt(t+2<nT?6:0) => t+1 landed.
// buf(t+2)=buf(t-1), last read 3 barriers earlier -> race-free.
__global__ __launch_bounds__(512, 2) void gemm_pv(const unsigned short* __restrict__ Sc,
                                                  const unsigned short* __restrict__ B, int ldb,
                                                  float* __restrict__ C, int ldc,
                                                  long long sA, long long sB, long long sC) {
  const int p = (int)(blockIdx.x >> 2);  // 0..15 pair index
  const int bx = blockIdx.x & 3;
  const unsigned short* Ab = Sc + (long long)blockIdx.z * sA;
  B += (long long)blockIdx.z * sB;
  C += (long long)blockIdx.z * sC;
  const int colBase = bx * 256;

  __shared__ unsigned short lds[73728];  // 144 KiB (3 bufs x 48 KiB)

  const int tid = threadIdx.x;
  const int wave = tid >> 6;
  const int lane = tid & 63;
  const int wr = wave >> 2;  // 0..1 (M half of 128)
  const int wc = wave & 3;   // 0..3 (N quarter)

  const int rS = tid >> 2;                            // 0..127
  const int ceS = ((tid & 3) * 8) ^ ((rS & 8) << 1);  // swizzled k-el in 32-chunk
  const unsigned short* sBp[2][2];
#pragma unroll
  for (int h = 0; h < 2; ++h)
#pragma unroll
    for (int c = 0; c < 2; ++c)
      sBp[h][c] = B + (size_t)(colBase + h * 128 + rS) * ldb + c * 32 + ceS;

  const int laneRow = lane & 15;
  const int csw = ((lane >> 4) * 8) ^ ((laneRow & 8) << 1);
  const int aBase = wr * 2048 + laneRow * 32 + csw;
  const int bBase = 8192 + (wc >> 1) * 8192 + ((wc & 1) * 64 + laneRow) * 32 + csw;
  const int er = lane & 15;
  const int ec = (lane >> 4) * 4;

  bf16x8 af[4][2];
  bf16x8 bq[2][2][2];

#define LOAD_ALL(CO)                                                                     \
  _Pragma("unroll") for (int i_ = 0; i_ < 4; ++i_)                                       \
  _Pragma("unroll") for (int ks_ = 0; ks_ < 2; ++ks_)                                    \
      af[i_][ks_] = *(const bf16x8*)&lds[(CO) + aBase + ks_ * 4096 + i_ * 512];          \
  _Pragma("unroll") for (int q_ = 0; q_ < 2; ++q_)                                       \
  _Pragma("unroll") for (int j_ = 0; j_ < 2; ++j_)                                       \
  _Pragma("unroll") for (int ks_ = 0; ks_ < 2; ++ks_)                                    \
      bq[q_][j_][ks_] = *(const bf16x8*)&lds[(CO) + bBase + ks_ * 4096 + (q_ * 2 + j_) * 512];

#define MFMA_Q(qn)                                                                       \
  {                                                                                      \
    __builtin_amdgcn_s_setprio(1);                                                       \
    _Pragma("unroll") for (int i_ = 0; i_ < 4; ++i_)                                     \
    _Pragma("unroll") for (int j_ = 0; j_ < 2; ++j_)                                     \
    _Pragma("unroll") for (int ks_ = 0; ks_ < 2; ++ks_)                                  \
        acc[i_][(qn)*2 + j_] = __builtin_amdgcn_mfma_f32_16x16x32_bf16(                  \
            bq[qn][j_][ks_], af[i_][ks_], acc[i_][(qn)*2 + j_], 0, 0, 0);                \
    __builtin_amdgcn_s_setprio(0);                                                       \
  }

#define BAR() __builtin_amdgcn_s_barrier()
#define WLG0()                                             \
  {                                                        \
    asm volatile("s_waitcnt lgkmcnt(0)" ::: "memory");     \
    __builtin_amdgcn_sched_barrier(0);                     \
  }

  for (int seg = 0; seg < 2; ++seg) {
    const int by = seg ? p : 31 - p;  // deep first, then shallow
    const int rowBase = by * 128;
    const int nT = 2 * (by + 1);  // 64-el k-tiles (even, >=2)
    const unsigned short* A = Ab + (size_t)(by * (by + 1) / 2) * TRI_BLK;
    const unsigned short* sAp0 = A + rS * 128 + ceS;
    const unsigned short* sAp1 = sAp0 + 32;

    auto STAGE_A = [&](int tau, int bufsel) {
      if (tau < nT) {
        long long o = (long long)(tau >> 1) * TRI_BLK + (tau & 1) * 64;
        unsigned short* d = &lds[bufsel * 24576 + wave * 512];
        load16_to_lds(sAp0 + o, d);
        load16_to_lds(sAp1 + o, d + 4096);
      }
    };
    auto STAGE_B = [&](int h, int tau, int bufsel) {
      if (tau < nT) {
        unsigned short* d = &lds[bufsel * 24576 + 8192 + h * 8192 + wave * 512];
        load16_to_lds(sBp[h][0] + tau * 64, d);
        load16_to_lds(sBp[h][1] + tau * 64, d + 4096);
      }
    };

    f32x4 acc[4][4];
#pragma unroll
    for (int i = 0; i < 4; ++i)
#pragma unroll
      for (int j = 0; j < 4; ++j) {
        f32x4 z = {0.f, 0.f, 0.f, 0.f};
        acc[i][j] = z;
      }

    // prologue: tile0 -> buf0 (6 ops), tile1 -> buf1 (6 ops)
    STAGE_A(0, 0);
    STAGE_B(0, 0, 0);
    STAGE_B(1, 0, 0);
    STAGE_A(1, 1);
    STAGE_B(0, 1, 1);
    STAGE_B(1, 1, 1);
    asm volatile("s_waitcnt vmcnt(6)" ::: "memory");  // tile 0 landed; tile 1 may fly
    BAR();

    int bsel = 0;
    for (int t = 0; t < nT; ++t) {
      const int tn = t + 2;
      int bn = bsel + 2; if (bn >= 3) bn -= 3;
      const int CO = bsel * 24576;

      // ---- phase 1: all 16 ds_reads of tile t; issue A(t+2); MFMA qn0 ----
      LOAD_ALL(CO);
      STAGE_A(tn, bn);
      BAR();
      WLG0();
      MFMA_Q(0);
      BAR();
      // ---- phase 2: issue B(t+2); counted vmcnt => tile t+1 landed; MFMA qn1 ----
      STAGE_B(0, tn, bn);
      STAGE_B(1, tn, bn);
      if (tn < nT) { asm volatile("s_waitcnt vmcnt(6)" ::: "memory"); }
      else         { asm volatile("s_waitcnt vmcnt(0)" ::: "memory"); }
      BAR();
      MFMA_Q(1);
      BAR();

      ++bsel; if (bsel >= 3) bsel = 0;
    }

    // ---- epilogue for this segment ----
#pragma unroll
    for (int fi = 0; fi < 4; ++fi)
#pragma unroll
      for (int fj = 0; fj < 4; ++fj) {
        size_t base = (size_t)(rowBase + wr * 64 + fi * 16 + er) * ldc +
                      (size_t)(colBase + wc * 64 + fj * 16 + ec);
        *(f32x4*)(C + base) = acc[fi][fj];
      }
  }
#undef LOAD_ALL
#undef MFMA_Q
#undef BAR
#undef WLG0
}

// ---------- in-place causal softmax over PACKED-TRI bf16 scores ----------
__global__ __launch_bounds__(256) void softmax_causal(unsigned short* __restrict__ Sc) {
  const int r = blockIdx.x;
  const int by = r >> 7;
  unsigned short* rowB = Sc + (size_t)blockIdx.y * PER_BATCH_EL +
                         (size_t)(by * (by + 1) / 2) * TRI_BLK + (size_t)(r & 127) * 128;
  const int ncols = (by + 1) << 7;  // multiple of 128
  const int tid = threadIdx.x;
  const int nIt = (ncols + 2047) >> 11;  // ceil(ncols / (256*8)) <= 2

  float v[16];
#pragma unroll
  for (int e = 0; e < 16; ++e) v[e] = -1e30f;
  float m = -1e30f;
#pragma unroll 2
  for (int it = 0; it < nIt; ++it) {
    int j0 = (it << 11) + tid * 8;  // 8 | 128 -> chunk stays in one segment
    if (j0 < ncols) {
      uint4 u = *(const uint4*)(rowB + ((j0 >> 7) << 14) + (j0 & 127));
      const unsigned short* us = (const unsigned short*)&u;
#pragma unroll
      for (int e = 0; e < 8; ++e) {
        float x = bf2f(us[e]);
        x = (j0 + e <= r) ? x : -1e30f;
        v[it * 8 + e] = x;
        m = fmaxf(m, x);
      }
    }
  }
  __shared__ float red[4];
  for (int off = 32; off; off >>= 1) m = fmaxf(m, __shfl_xor(m, off, 64));
  if ((tid & 63) == 0) red[tid >> 6] = m;
  __syncthreads();
  m = fmaxf(fmaxf(red[0], red[1]), fmaxf(red[2], red[3]));
  __syncthreads();

  float s = 0.f;
#pragma unroll
  for (int e = 0; e < 16; ++e) {
    float x = v[e];
    float ex = (x > -1e29f) ? __expf(x - m) : 0.f;
    v[e] = ex;
    s += ex;
  }
  for (int off = 32; off; off >>= 1) s += __shfl_xor(s, off, 64);
  if ((tid & 63) == 0) red[tid >> 6] = s;
  __syncthreads();
  s = red[0] + red[1] + red[2] + red[3];
  float inv = 1.f / s;

#pragma unroll 2
  for (int it = 0; it < nIt; ++it) {
    int j0 = (it << 11) + tid * 8;
    if (j0 < ncols) {
      uint4 o;
      unsigned int* po = (unsigned int*)&o;
#pragma unroll
      for (int e = 0; e < 4; ++e)
        po[e] = pack_bf16_trunc(v[it * 8 + 2 * e] * inv, v[it * 8 + 2 * e + 1] * inv);
      *(uint4*)(rowB + ((j0 >> 7) << 14) + (j0 & 127)) = o;
    }
  }
}

// ---------- launch ----------
extern "C" void kernel_launch(void* const* d_in, const int* in_sizes, int n_in,
                              void* d_out, int out_size, void* d_ws, size_t ws_size,
                              hipStream_t stream) {
  const float* X  = (const float*)d_in[0];
  const float* Wq = (const float*)d_in[1];
  const float* Wk = (const float*)d_in[2];
  const float* Wv = (const float*)d_in[3];
  float* out = (float*)d_out;

  const int Bsz = 4, S = 4096, D = 1024;
  const long long MD = (long long)Bsz * S;  // 16384 total rows
  const long long elBig = MD * D;           // 16,777,216

  // ws layout (bf16 el): Wb[3DD] Qb[elBig] Kb[elBig] Vt[elBig] Xb[elBig]...
  // Sc ALIASES Xb (Xb dead after projections; stream order makes reuse safe).
  unsigned short* Wb = (unsigned short*)d_ws;
  unsigned short* Qb = Wb + 3LL * D * D;
  unsigned short* Kb = Qb + elBig;
  unsigned short* Vt = Kb + elBig;
  unsigned short* Xb = Vt + elBig;
  unsigned short* Sc = Xb;  // packed-tri, PER_BATCH_EL per batch

  const long long offXb = 3LL * D * D + 3LL * elBig;
  auto needB = [&](int nb) {
    long long tail = (long long)nb * PER_BATCH_EL;
    if (tail < elBig) tail = elBig;
    return (size_t)((offXb + tail) * 2);
  };
  int nb = 1;
  if (ws_size >= needB(4)) nb = 4;        // 176.2 MB
  else if (ws_size >= needB(2)) nb = 2;   // 141.6 MB

  // 1) casts
  cast_f32_to_bf16<<<dim3((unsigned)(elBig / 4 / 256)), 256, 0, stream>>>(X, Xb, (int)(elBig / 4));
  cast_f32_to_bf16<<<dim3((unsigned)((long long)D * D / 4 / 256)), 256, 0, stream>>>(Wq, Wb, D * D / 4);
  cast_f32_to_bf16<<<dim3((unsigned)((long long)D * D / 4 / 256)), 256, 0, stream>>>(Wk, Wb + (long long)D * D, D * D / 4);
  cast_f32_to_bf16<<<dim3((unsigned)((long long)D * D / 4 / 256)), 256, 0, stream>>>(Wv, Wb + 2LL * D * D, D * D / 4);

  // 2) Q,K projections: C[s][e] = X[s,:].W[e,:]  (z picks Wq/Wk -> Qb/Kb)
  gemm8<0><<<dim3(D / 256, (unsigned)(MD / 256), 2), 512, 0, stream>>>(
      Xb, D, Wb, D, (void*)Qb, D, D, 1.f, 0LL, (long long)D * D, elBig);
  // 3) V produced transposed: Vt[e][s] = Wv[e,:].X[s,:]
  gemm8<0><<<dim3((unsigned)(MD / 256), D / 256, 1), 512, 0, stream>>>(
      Wb + 2LL * D * D, D, Xb, D, (void*)Vt, (int)MD, D, 1.f, 0LL, 0LL, 0LL);

  // 4) per-batch-group: scores(packed tri) -> softmax -> PV (paired 128-row tiles)
  const float sscale = 1.0f / 32.0f;  // 1/sqrt(1024)
  for (int b0 = 0; b0 < Bsz; b0 += nb) {
    gemm8<1><<<dim3(136, 1, nb), 512, 0, stream>>>(
        Qb + (long long)b0 * S * D, D, Kb + (long long)b0 * S * D, D, (void*)Sc, 0, D, sscale,
        (long long)S * D, (long long)S * D, (long long)PER_BATCH_EL);
    softmax_causal<<<dim3(S, nb), 256, 0, stream>>>(Sc);
    gemm_pv<<<dim3(64, 1, nb), 512, 0, stream>>>(
        Sc, Vt + (long long)b0 * S, (int)MD, out + (long long)b0 * S * D, D,
        (long long)PER_BATCH_EL, (long long)S, (long long)S * D);
  }
}

// Round 6
// 455.244 us; speedup vs baseline: 4.7909x; 4.7909x over previous
//
#include <hip/hip_runtime.h>

// ---------- helpers ----------
typedef __bf16 bf16x8 __attribute__((ext_vector_type(8)));
typedef float f32x4 __attribute__((ext_vector_type(4)));

__device__ __forceinline__ float bf2f(unsigned short u) {
  union { unsigned int i; float f; } x;
  x.i = ((unsigned int)u) << 16;
  return x.f;
}
__device__ __forceinline__ unsigned short f2bf(float f) {
  union { float f; unsigned int i; } x;
  x.f = f;
  unsigned int u = x.i;
  u += 0x7fffu + ((u >> 16) & 1u);  // RNE
  return (unsigned short)(u >> 16);
}
__device__ __forceinline__ unsigned int fbits(float f) {
  union { float f; unsigned int i; } x; x.f = f; return x.i;
}
// pack two fp32 -> two truncated bf16 in ONE v_perm_b32
__device__ __forceinline__ unsigned int pack_bf16_trunc(float lo, float hi) {
  return __builtin_amdgcn_perm(fbits(hi), fbits(lo), 0x07060302u);
}

// async global->LDS, 16B per lane, LDS dest wave-uniform base (lane auto-offsets by 16B)
__device__ __forceinline__ void load16_to_lds(const void* g, void* l) {
  __builtin_amdgcn_global_load_lds(
      (__attribute__((address_space(1))) void*)const_cast<void*>(g),
      (__attribute__((address_space(3))) void*)l, 16, 0, 0);
}

// packed lower-triangle score buffer: 528 blocks of 128x128 bf16, block-linear.
// block (by,bx), bx<=by, stored at (by*(by+1)/2 + bx)*16384; elem (r,c) at +r*128+c.
#define TRI_BLK 16384
#define TRI_NBLK 528
#define PER_BATCH_EL (TRI_NBLK * TRI_BLK)  // 8,650,752 el = 17.3 MB

// ---------- fused cast fp32 -> bf16 for X, Wq, Wk, Wv (one dispatch) ----------
// i < n4x: X -> Xb; else 3 weight segments of n4w float4 each -> Wb (contig).
__global__ __launch_bounds__(256) void cast_all(const float* __restrict__ X,
                                                const float* __restrict__ Wq,
                                                const float* __restrict__ Wk,
                                                const float* __restrict__ Wv,
                                                unsigned short* __restrict__ Xb,
                                                unsigned short* __restrict__ Wb,
                                                int n4x, int n4w) {
  int i = blockIdx.x * 256 + threadIdx.x;
  const float* s;
  unsigned short* d;
  int off;
  if (i < n4x) {
    s = X; d = Xb; off = i;
  } else {
    int j = i - n4x;
    int seg = j / n4w;  // n4w is a power of two -> shift
    off = j - seg * n4w;
    s = (seg == 0) ? Wq : ((seg == 1) ? Wk : Wv);
    d = Wb + (long long)seg * n4w * 4;
  }
  float4 f = ((const float4*)s)[off];
  ushort4 o;
  o.x = f2bf(f.x); o.y = f2bf(f.y); o.z = f2bf(f.z); o.w = f2bf(f.w);
  ((ushort4*)d)[off] = o;
}

// ---------- 256x256 8-phase NT GEMM: C[m][n] = sum_k A[m][k] * B[n][k] ----------
// BM=BN=256, BK=64, 8 waves (2M x 4N), 512 threads, 128 KiB LDS.
// NOTE: (512,2) is mandatory — acc[8][4]=128 AGPR + ~124 VGPR = 252 of the
// 256-reg unified cap at 2 waves/EU. (512,4) caps at 128 -> catastrophic spill (R5).
// MODE 0: proj   -> bf16 C row-major, grid (N/256, M/256, z)
// MODE 1: scores -> bf16*scale into PACKED-TRI (128-blocks), grid (136, 1, nb)
template <int MODE>
__global__ __launch_bounds__(512, 2) void gemm8(const unsigned short* __restrict__ A, int lda,
                                                const unsigned short* __restrict__ B, int ldb,
                                                void* __restrict__ Cv, int ldc, int K, float scale,
                                                long long sA, long long sB, long long sC) {
  int by, bx;
  if constexpr (MODE == 1) {
    int b = blockIdx.x;
    by = (int)((__fsqrt_rn(8.f * b + 1.f) - 1.f) * 0.5f);
    while ((by + 1) * (by + 2) / 2 <= b) ++by;
    while (by * (by + 1) / 2 > b) --by;
    bx = b - by * (by + 1) / 2;
  } else {
    by = blockIdx.y;
    bx = blockIdx.x;
  }
  A += (long long)blockIdx.z * sA;
  B += (long long)blockIdx.z * sB;

  const int rowBase = by * 256;
  const int colBase = bx * 256;

  __shared__ unsigned short lds[65536];  // 128 KiB

  const int tid = threadIdx.x;
  const int wave = tid >> 6;
  const int lane = tid & 63;
  const int wr = wave >> 2;  // 0..1  (M half)
  const int wc = wave & 3;   // 0..3  (N quarter)

  // ---- staging source precompute (pre-swizzled global addresses) ----
  const int rS = (tid >> 2) & 127;                       // row within half-tile
  const int ceS = ((tid & 3) * 8) ^ ((rS & 8) << 1);     // logical k-el offset in 32-chunk
  const unsigned short* sAp[2][2];
  const unsigned short* sBp[2][2];
#pragma unroll
  for (int h = 0; h < 2; ++h)
#pragma unroll
    for (int c = 0; c < 2; ++c) {
      sAp[h][c] = A + (size_t)(rowBase + h * 128 + rS) * lda + c * 32 + ceS;
      sBp[h][c] = B + (size_t)(colBase + h * 128 + rS) * ldb + c * 32 + ceS;
    }
  const int nT = K >> 6;  // 64-el k-tiles
  const int nIter = nT >> 1;

  // ---- LDS read bases (swizzled) ----
  const int laneRow = lane & 15;
  const int csw = ((lane >> 4) * 8) ^ ((laneRow & 8) << 1);
  const int aBase = wr * 8192 + laneRow * 32 + csw;
  const int bBase = 16384 + (wc >> 1) * 8192 + ((wc & 1) * 64 + laneRow) * 32 + csw;

  f32x4 acc[8][4];
#pragma unroll
  for (int i = 0; i < 8; ++i)
#pragma unroll
    for (int j = 0; j < 4; ++j) {
      f32x4 z = {0.f, 0.f, 0.f, 0.f};
      acc[i][j] = z;
    }
  bf16x8 af[4][2];      // current qm: 4 M-frags x 2 k-slices
  bf16x8 bq[2][2][2];   // both qn: [qn][j][ks]

  auto STAGE_A = [&](int h, int tau, int bufsel) {
    if (tau < nT) {
      unsigned short* d = &lds[bufsel * 32768 + h * 8192 + wave * 512];
      load16_to_lds(sAp[h][0] + tau * 64, d);
      load16_to_lds(sAp[h][1] + tau * 64, d + 4096);
    }
  };
  auto STAGE_B = [&](int h, int tau, int bufsel) {
    if (tau < nT) {
      unsigned short* d = &lds[bufsel * 32768 + 16384 + h * 8192 + wave * 512];
      load16_to_lds(sBp[h][0] + tau * 64, d);
      load16_to_lds(sBp[h][1] + tau * 64, d + 4096);
    }
  };

#define LOAD_A(qm, CO)                                                                   \
  _Pragma("unroll") for (int i_ = 0; i_ < 4; ++i_)                                       \
  _Pragma("unroll") for (int ks_ = 0; ks_ < 2; ++ks_)                                    \
      af[i_][ks_] = *(const bf16x8*)&lds[(CO) + aBase + ks_ * 4096 + ((qm)*4 + i_) * 512];

#define LOAD_B(qn, CO)                                                                   \
  _Pragma("unroll") for (int j_ = 0; j_ < 2; ++j_)                                       \
  _Pragma("unroll") for (int ks_ = 0; ks_ < 2; ++ks_)                                    \
      bq[qn][j_][ks_] = *(const bf16x8*)&lds[(CO) + bBase + ks_ * 4096 + ((qn)*2 + j_) * 512];

#define MFMA_Q(qm, qn)                                                                   \
  {                                                                                      \
    __builtin_amdgcn_s_setprio(1);                                                       \
    _Pragma("unroll") for (int i_ = 0; i_ < 4; ++i_)                                     \
    _Pragma("unroll") for (int j_ = 0; j_ < 2; ++j_)                                     \
    _Pragma("unroll") for (int ks_ = 0; ks_ < 2; ++ks_)                                  \
        acc[(qm)*4 + i_][(qn)*2 + j_] = __builtin_amdgcn_mfma_f32_16x16x32_bf16(         \
            bq[qn][j_][ks_], af[i_][ks_], acc[(qm)*4 + i_][(qn)*2 + j_], 0, 0, 0);       \
    __builtin_amdgcn_s_setprio(0);                                                       \
  }

#define BAR() __builtin_amdgcn_s_barrier()
#define WLG0()                                             \
  {                                                        \
    asm volatile("s_waitcnt lgkmcnt(0)" ::: "memory");     \
    __builtin_amdgcn_sched_barrier(0);                     \
  }

  // ---- prologue: A(0),B(0) -> buf0; B(1) -> buf1 ----
  STAGE_A(0, 0, 0);
  STAGE_A(1, 0, 0);
  STAGE_B(0, 0, 0);
  STAGE_B(1, 0, 0);
  STAGE_B(0, 1, 1);
  STAGE_B(1, 1, 1);
  asm volatile("s_waitcnt vmcnt(4)" ::: "memory");  // tile 0 landed; B(1) may fly
  BAR();

  for (int it = 0; it < nIter; ++it) {
    const int ta = 2 * it + 1, tb = 2 * it + 2, tc = 2 * it + 3;
    const bool sb = tb < nT, sc = tc < nT;

    // ---- phase 1: tile t0 (buf0), quadrant (0,0) ----
    LOAD_A(0, 0);
    LOAD_B(0, 0);
    STAGE_A(0, ta, 1);
    BAR();
    WLG0();
    MFMA_Q(0, 0);
    BAR();
    // ---- phase 2: (0,1) ----
    LOAD_B(1, 0);
    STAGE_A(1, ta, 1);
    BAR();
    WLG0();
    MFMA_Q(0, 1);
    BAR();
    // ---- phase 3: (1,0) ----
    LOAD_A(1, 0);
    STAGE_B(0, tb, 0);
    BAR();
    WLG0();
    MFMA_Q(1, 0);
    BAR();
    // ---- phase 4: (1,1) + vmcnt ----
    STAGE_B(1, tb, 0);
    if (sb) { asm volatile("s_waitcnt vmcnt(4)" ::: "memory"); }
    else    { asm volatile("s_waitcnt vmcnt(0)" ::: "memory"); }
    BAR();
    MFMA_Q(1, 1);
    BAR();
    // ---- phase 5: tile t1 (buf1), quadrant (0,0) ----
    LOAD_A(0, 32768);
    LOAD_B(0, 32768);
    STAGE_A(0, tb, 0);
    BAR();
    WLG0();
    MFMA_Q(0, 0);
    BAR();
    // ---- phase 6: (0,1) ----
    LOAD_B(1, 32768);
    STAGE_A(1, tb, 0);
    BAR();
    WLG0();
    MFMA_Q(0, 1);
    BAR();
    // ---- phase 7: (1,0) ----
    LOAD_A(1, 32768);
    STAGE_B(0, tc, 1);
    BAR();
    WLG0();
    MFMA_Q(1, 0);
    BAR();
    // ---- phase 8: (1,1) + vmcnt ----
    STAGE_B(1, tc, 1);
    if (sc) { asm volatile("s_waitcnt vmcnt(4)" ::: "memory"); }
    else    { asm volatile("s_waitcnt vmcnt(0)" ::: "memory"); }
    BAR();
    MFMA_Q(1, 1);
    BAR();
  }

  // ---- epilogue: lane holds C[row=16fi+er][cols=16fj+ec..+3] per frag ----
  const int er = lane & 15;
  const int ec = (lane >> 4) * 4;
  if constexpr (MODE == 1) {
    const int rbB = 2 * by + wr;
    const int cbB = 2 * bx + (wc >> 1);
    if (cbB <= rbB) {  // skip upper quadrant of diagonal 256-tiles (not stored)
      unsigned short* C = (unsigned short*)Cv + (long long)blockIdx.z * sC +
                          (size_t)(rbB * (rbB + 1) / 2 + cbB) * TRI_BLK;
#pragma unroll
      for (int fi = 0; fi < 8; ++fi)
#pragma unroll
        for (int fj = 0; fj < 4; ++fj) {
          f32x4 a = acc[fi][fj];
          a[0] *= scale; a[1] *= scale; a[2] *= scale; a[3] *= scale;
          uint2 p;
          p.x = pack_bf16_trunc(a[0], a[1]);
          p.y = pack_bf16_trunc(a[2], a[3]);
          int row = fi * 16 + er;
          int col = (wc & 1) * 64 + fj * 16 + ec;
          *(uint2*)(C + row * 128 + col) = p;
        }
    }
  } else {
    unsigned short* C = (unsigned short*)Cv + (long long)blockIdx.z * sC;
#pragma unroll
    for (int fi = 0; fi < 8; ++fi)
#pragma unroll
      for (int fj = 0; fj < 4; ++fj) {
        uint2 p;
        p.x = pack_bf16_trunc(acc[fi][fj][0], acc[fi][fj][1]);
        p.y = pack_bf16_trunc(acc[fi][fj][2], acc[fi][fj][3]);
        size_t base = (size_t)(rowBase + wr * 128 + fi * 16 + er) * ldc +
                      (size_t)(colBase + wc * 64 + fj * 16 + ec);
        *(uint2*)(C + base) = p;
      }
  }
#undef LOAD_A
#undef LOAD_B
#undef MFMA_Q
#undef BAR
#undef WLG0
}

// ---------- PV: paired 128x256 tiles, 3-buffer deep pipeline ----------
// One block = TWO row-blocks (byDeep=31-p, byShallow=p): depth sum
// 2(32-p)+2(p+1) = 66 k-tiles CONSTANT -> perfect balance, 256 equal blocks.
// Per segment: C[128r][256c] = sum_k P[r][k]*Vt[c][k]; P packed-tri row-block by,
// K = 128*(by+1) (diag upper-tri zeros from softmax). 8 waves (2Mx4N), 64x64/wave.
// LDS 3 bufs x 24576 el (144 KiB). Pipeline depth 2 tiles: compute t (buf t%3),
// t+1 landed, t+2 issuing; vmcnt(6) at P2. READ-SPLIT (R6): P1 reads af+bq[0]
// (12 ds_reads), P2 reads bq[1] (4) — shortens each phase's lgkm chain vs the
// previous 16-read clump. Buf t is not overwritten until t+3 -> P2 reads safe.
__global__ __launch_bounds__(512, 2) void gemm_pv(const unsigned short* __restrict__ Sc,
                                                  const unsigned short* __restrict__ B, int ldb,
                                                  float* __restrict__ C, int ldc,
                                                  long long sA, long long sB, long long sC) {
  const int p = (int)(blockIdx.x >> 2);  // 0..15 pair index
  const int bx = blockIdx.x & 3;
  const unsigned short* Ab = Sc + (long long)blockIdx.z * sA;
  B += (long long)blockIdx.z * sB;
  C += (long long)blockIdx.z * sC;
  const int colBase = bx * 256;

  __shared__ unsigned short lds[73728];  // 144 KiB (3 bufs x 48 KiB)

  const int tid = threadIdx.x;
  const int wave = tid >> 6;
  const int lane = tid & 63;
  const int wr = wave >> 2;  // 0..1 (M half of 128)
  const int wc = wave & 3;   // 0..3 (N quarter)

  const int rS = tid >> 2;                            // 0..127
  const int ceS = ((tid & 3) * 8) ^ ((rS & 8) << 1);  // swizzled k-el in 32-chunk
  const unsigned short* sBp[2][2];
#pragma unroll
  for (int h = 0; h < 2; ++h)
#pragma unroll
    for (int c = 0; c < 2; ++c)
      sBp[h][c] = B + (size_t)(colBase + h * 128 + rS) * ldb + c * 32 + ceS;

  const int laneRow = lane & 15;
  const int csw = ((lane >> 4) * 8) ^ ((laneRow & 8) << 1);
  const int aBase = wr * 2048 + laneRow * 32 + csw;
  const int bBase = 8192 + (wc >> 1) * 8192 + ((wc & 1) * 64 + laneRow) * 32 + csw;
  const int er = lane & 15;
  const int ec = (lane >> 4) * 4;

  bf16x8 af[4][2];
  bf16x8 bq[2][2][2];

#define LOAD_P1(CO)                                                                      \
  _Pragma("unroll") for (int i_ = 0; i_ < 4; ++i_)                                       \
  _Pragma("unroll") for (int ks_ = 0; ks_ < 2; ++ks_)                                    \
      af[i_][ks_] = *(const bf16x8*)&lds[(CO) + aBase + ks_ * 4096 + i_ * 512];          \
  _Pragma("unroll") for (int j_ = 0; j_ < 2; ++j_)                                       \
  _Pragma("unroll") for (int ks_ = 0; ks_ < 2; ++ks_)                                    \
      bq[0][j_][ks_] = *(const bf16x8*)&lds[(CO) + bBase + ks_ * 4096 + j_ * 512];

#define LOAD_P2(CO)                                                                      \
  _Pragma("unroll") for (int j_ = 0; j_ < 2; ++j_)                                       \
  _Pragma("unroll") for (int ks_ = 0; ks_ < 2; ++ks_)                                    \
      bq[1][j_][ks_] = *(const bf16x8*)&lds[(CO) + bBase + ks_ * 4096 + (2 + j_) * 512];

#define MFMA_Q(qn)                                                                       \
  {                                                                                      \
    __builtin_amdgcn_s_setprio(1);                                                       \
    _Pragma("unroll") for (int i_ = 0; i_ < 4; ++i_)                                     \
    _Pragma("unroll") for (int j_ = 0; j_ < 2; ++j_)                                     \
    _Pragma("unroll") for (int ks_ = 0; ks_ < 2; ++ks_)                                  \
        acc[i_][(qn)*2 + j_] = __builtin_amdgcn_mfma_f32_16x16x32_bf16(                  \
            bq[qn][j_][ks_], af[i_][ks_], acc[i_][(qn)*2 + j_], 0, 0, 0);                \
    __builtin_amdgcn_s_setprio(0);                                                       \
  }

#define BAR() __builtin_amdgcn_s_barrier()
#define WLG0()                                             \
  {                                                        \
    asm volatile("s_waitcnt lgkmcnt(0)" ::: "memory");     \
    __builtin_amdgcn_sched_barrier(0);                     \
  }

  for (int seg = 0; seg < 2; ++seg) {
    const int by = seg ? p : 31 - p;  // deep first, then shallow
    const int rowBase = by * 128;
    const int nT = 2 * (by + 1);  // 64-el k-tiles (even, >=2)
    const unsigned short* A = Ab + (size_t)(by * (by + 1) / 2) * TRI_BLK;
    const unsigned short* sAp0 = A + rS * 128 + ceS;
    const unsigned short* sAp1 = sAp0 + 32;

    auto STAGE_A = [&](int tau, int bufsel) {
      if (tau < nT) {
        long long o = (long long)(tau >> 1) * TRI_BLK + (tau & 1) * 64;
        unsigned short* d = &lds[bufsel * 24576 + wave * 512];
        load16_to_lds(sAp0 + o, d);
        load16_to_lds(sAp1 + o, d + 4096);
      }
    };
    auto STAGE_B = [&](int h, int tau, int bufsel) {
      if (tau < nT) {
        unsigned short* d = &lds[bufsel * 24576 + 8192 + h * 8192 + wave * 512];
        load16_to_lds(sBp[h][0] + tau * 64, d);
        load16_to_lds(sBp[h][1] + tau * 64, d + 4096);
      }
    };

    f32x4 acc[4][4];
#pragma unroll
    for (int i = 0; i < 4; ++i)
#pragma unroll
      for (int j = 0; j < 4; ++j) {
        f32x4 z = {0.f, 0.f, 0.f, 0.f};
        acc[i][j] = z;
      }

    // prologue: tile0 -> buf0 (6 ops), tile1 -> buf1 (6 ops)
    STAGE_A(0, 0);
    STAGE_B(0, 0, 0);
    STAGE_B(1, 0, 0);
    STAGE_A(1, 1);
    STAGE_B(0, 1, 1);
    STAGE_B(1, 1, 1);
    asm volatile("s_waitcnt vmcnt(6)" ::: "memory");  // tile 0 landed; tile 1 may fly
    BAR();

    int bsel = 0;
    for (int t = 0; t < nT; ++t) {
      const int tn = t + 2;
      int bn = bsel + 2; if (bn >= 3) bn -= 3;
      const int CO = bsel * 24576;

      // ---- phase 1: af + bq[0] ds_reads (12); issue A(t+2); MFMA qn0 ----
      LOAD_P1(CO);
      STAGE_A(tn, bn);
      BAR();
      WLG0();
      MFMA_Q(0);
      BAR();
      // ---- phase 2: bq[1] ds_reads (4); issue B(t+2); counted vmcnt; MFMA qn1 ----
      LOAD_P2(CO);
      STAGE_B(0, tn, bn);
      STAGE_B(1, tn, bn);
      if (tn < nT) { asm volatile("s_waitcnt vmcnt(6)" ::: "memory"); }
      else         { asm volatile("s_waitcnt vmcnt(0)" ::: "memory"); }
      BAR();
      WLG0();
      MFMA_Q(1);
      BAR();

      ++bsel; if (bsel >= 3) bsel = 0;
    }

    // ---- epilogue for this segment ----
#pragma unroll
    for (int fi = 0; fi < 4; ++fi)
#pragma unroll
      for (int fj = 0; fj < 4; ++fj) {
        size_t base = (size_t)(rowBase + wr * 64 + fi * 16 + er) * ldc +
                      (size_t)(colBase + wc * 64 + fj * 16 + ec);
        *(f32x4*)(C + base) = acc[fi][fj];
      }
  }
#undef LOAD_P1
#undef LOAD_P2
#undef MFMA_Q
#undef BAR
#undef WLG0
}

// ---------- in-place causal softmax over PACKED-TRI bf16 scores ----------
__global__ __launch_bounds__(256) void softmax_causal(unsigned short* __restrict__ Sc) {
  const int r = blockIdx.x;
  const int by = r >> 7;
  unsigned short* rowB = Sc + (size_t)blockIdx.y * PER_BATCH_EL +
                         (size_t)(by * (by + 1) / 2) * TRI_BLK + (size_t)(r & 127) * 128;
  const int ncols = (by + 1) << 7;  // multiple of 128
  const int tid = threadIdx.x;
  const int nIt = (ncols + 2047) >> 11;  // ceil(ncols / (256*8)) <= 2

  float v[16];
#pragma unroll
  for (int e = 0; e < 16; ++e) v[e] = -1e30f;
  float m = -1e30f;
#pragma unroll 2
  for (int it = 0; it < nIt; ++it) {
    int j0 = (it << 11) + tid * 8;  // 8 | 128 -> chunk stays in one segment
    if (j0 < ncols) {
      uint4 u = *(const uint4*)(rowB + ((j0 >> 7) << 14) + (j0 & 127));
      const unsigned short* us = (const unsigned short*)&u;
#pragma unroll
      for (int e = 0; e < 8; ++e) {
        float x = bf2f(us[e]);
        x = (j0 + e <= r) ? x : -1e30f;
        v[it * 8 + e] = x;
        m = fmaxf(m, x);
      }
    }
  }
  __shared__ float red[4];
  for (int off = 32; off; off >>= 1) m = fmaxf(m, __shfl_xor(m, off, 64));
  if ((tid & 63) == 0) red[tid >> 6] = m;
  __syncthreads();
  m = fmaxf(fmaxf(red[0], red[1]), fmaxf(red[2], red[3]));
  __syncthreads();

  float s = 0.f;
#pragma unroll
  for (int e = 0; e < 16; ++e) {
    float x = v[e];
    float ex = (x > -1e29f) ? __expf(x - m) : 0.f;
    v[e] = ex;
    s += ex;
  }
  for (int off = 32; off; off >>= 1) s += __shfl_xor(s, off, 64);
  if ((tid & 63) == 0) red[tid >> 6] = s;
  __syncthreads();
  s = red[0] + red[1] + red[2] + red[3];
  float inv = 1.f / s;

#pragma unroll 2
  for (int it = 0; it < nIt; ++it) {
    int j0 = (it << 11) + tid * 8;
    if (j0 < ncols) {
      uint4 o;
      unsigned int* po = (unsigned int*)&o;
#pragma unroll
      for (int e = 0; e < 4; ++e)
        po[e] = pack_bf16_trunc(v[it * 8 + 2 * e] * inv, v[it * 8 + 2 * e + 1] * inv);
      *(uint4*)(rowB + ((j0 >> 7) << 14) + (j0 & 127)) = o;
    }
  }
}

// ---------- launch ----------
extern "C" void kernel_launch(void* const* d_in, const int* in_sizes, int n_in,
                              void* d_out, int out_size, void* d_ws, size_t ws_size,
                              hipStream_t stream) {
  const float* X  = (const float*)d_in[0];
  const float* Wq = (const float*)d_in[1];
  const float* Wk = (const float*)d_in[2];
  const float* Wv = (const float*)d_in[3];
  float* out = (float*)d_out;

  const int Bsz = 4, S = 4096, D = 1024;
  const long long MD = (long long)Bsz * S;  // 16384 total rows
  const long long elBig = MD * D;           // 16,777,216

  // ws layout (bf16 el): Wb[3DD] Qb[elBig] Kb[elBig] Vt[elBig] Xb[elBig]...
  // Sc ALIASES Xb (Xb dead after projections; stream order makes reuse safe).
  unsigned short* Wb = (unsigned short*)d_ws;
  unsigned short* Qb = Wb + 3LL * D * D;
  unsigned short* Kb = Qb + elBig;
  unsigned short* Vt = Kb + elBig;
  unsigned short* Xb = Vt + elBig;
  unsigned short* Sc = Xb;  // packed-tri, PER_BATCH_EL per batch

  const long long offXb = 3LL * D * D + 3LL * elBig;
  auto needB = [&](int nb) {
    long long tail = (long long)nb * PER_BATCH_EL;
    if (tail < elBig) tail = elBig;
    return (size_t)((offXb + tail) * 2);
  };
  int nb = 1;
  if (ws_size >= needB(4)) nb = 4;        // 176.2 MB
  else if (ws_size >= needB(2)) nb = 2;   // 141.6 MB

  // 1) fused casts: X + Wq + Wk + Wv in one dispatch
  const int n4x = (int)(elBig / 4);          // 4,194,304
  const int n4w = D * D / 4;                 // 262,144 (pow2)
  const int n4tot = n4x + 3 * n4w;           // 4,980,736 = 19456 * 256
  cast_all<<<dim3((unsigned)(n4tot / 256)), 256, 0, stream>>>(X, Wq, Wk, Wv, Xb, Wb, n4x, n4w);

  // 2) Q,K projections: C[s][e] = X[s,:].W[e,:]  (z picks Wq/Wk -> Qb/Kb)
  gemm8<0><<<dim3(D / 256, (unsigned)(MD / 256), 2), 512, 0, stream>>>(
      Xb, D, Wb, D, (void*)Qb, D, D, 1.f, 0LL, (long long)D * D, elBig);
  // 3) V produced transposed: Vt[e][s] = Wv[e,:].X[s,:]
  gemm8<0><<<dim3((unsigned)(MD / 256), D / 256, 1), 512, 0, stream>>>(
      Wb + 2LL * D * D, D, Xb, D, (void*)Vt, (int)MD, D, 1.f, 0LL, 0LL, 0LL);

  // 4) per-batch-group: scores(packed tri) -> softmax -> PV (paired 128-row tiles)
  const float sscale = 1.0f / 32.0f;  // 1/sqrt(1024)
  for (int b0 = 0; b0 < Bsz; b0 += nb) {
    gemm8<1><<<dim3(136, 1, nb), 512, 0, stream>>>(
        Qb + (long long)b0 * S * D, D, Kb + (long long)b0 * S * D, D, (void*)Sc, 0, D, sscale,
        (long long)S * D, (long long)S * D, (long long)PER_BATCH_EL);
    softmax_causal<<<dim3(S, nb), 256, 0, stream>>>(Sc);
    gemm_pv<<<dim3(64, 1, nb), 512, 0, stream>>>(
        Sc, Vt + (long long)b0 * S, (int)MD, out + (long long)b0 * S * D, D,
        (long long)PER_BATCH_EL, (long long)S, (long long)S * D);
  }
}

// Round 7
// 435.139 us; speedup vs baseline: 5.0123x; 1.0462x over previous
//
#include <hip/hip_runtime.h>

// ---------- helpers ----------
typedef __bf16 bf16x8 __attribute__((ext_vector_type(8)));
typedef float f32x4 __attribute__((ext_vector_type(4)));

__device__ __forceinline__ float bf2f(unsigned short u) {
  union { unsigned int i; float f; } x;
  x.i = ((unsigned int)u) << 16;
  return x.f;
}
__device__ __forceinline__ unsigned short f2bf(float f) {
  union { float f; unsigned int i; } x;
  x.f = f;
  unsigned int u = x.i;
  u += 0x7fffu + ((u >> 16) & 1u);  // RNE
  return (unsigned short)(u >> 16);
}
__device__ __forceinline__ unsigned int fbits(float f) {
  union { float f; unsigned int i; } x; x.f = f; return x.i;
}
// pack two fp32 -> two truncated bf16 in ONE v_perm_b32
__device__ __forceinline__ unsigned int pack_bf16_trunc(float lo, float hi) {
  return __builtin_amdgcn_perm(fbits(hi), fbits(lo), 0x07060302u);
}

// async global->LDS, 16B per lane, LDS dest wave-uniform base (lane auto-offsets by 16B)
__device__ __forceinline__ void load16_to_lds(const void* g, void* l) {
  __builtin_amdgcn_global_load_lds(
      (__attribute__((address_space(1))) void*)const_cast<void*>(g),
      (__attribute__((address_space(3))) void*)l, 16, 0, 0);
}

// packed lower-triangle score buffer: 528 blocks of 128x128 bf16, block-linear.
// block (by,bx), bx<=by, stored at (by*(by+1)/2 + bx)*16384; elem (r,c) at +r*128+c.
#define TRI_BLK 16384
#define TRI_NBLK 528
#define PER_BATCH_EL (TRI_NBLK * TRI_BLK)  // 8,650,752 el = 17.3 MB

// XCD-chunking swizzle (T1): hw round-robins linear wg id over 8 XCDs; remap so
// logical (panel-sharing) order is CONTIGUOUS per XCD. Requires n % 8 == 0.
__device__ __forceinline__ int xcd_chunk(int u, int n) {
  return (u & 7) * (n >> 3) + (u >> 3);
}

// ---------- fused cast fp32 -> bf16 for X, Wq, Wk, Wv (one dispatch) ----------
__global__ __launch_bounds__(256) void cast_all(const float* __restrict__ X,
                                                const float* __restrict__ Wq,
                                                const float* __restrict__ Wk,
                                                const float* __restrict__ Wv,
                                                unsigned short* __restrict__ Xb,
                                                unsigned short* __restrict__ Wb,
                                                int n4x, int n4w) {
  int i = blockIdx.x * 256 + threadIdx.x;
  const float* s;
  unsigned short* d;
  int off;
  if (i < n4x) {
    s = X; d = Xb; off = i;
  } else {
    int j = i - n4x;
    int seg = j / n4w;  // n4w is a power of two -> shift
    off = j - seg * n4w;
    s = (seg == 0) ? Wq : ((seg == 1) ? Wk : Wv);
    d = Wb + (long long)seg * n4w * 4;
  }
  float4 f = ((const float4*)s)[off];
  ushort4 o;
  o.x = f2bf(f.x); o.y = f2bf(f.y); o.z = f2bf(f.z); o.w = f2bf(f.w);
  ((ushort4*)d)[off] = o;
}

// ---------- 256x256 8-phase NT GEMM: C[m][n] = sum_k A[m][k] * B[n][k] ----------
// BM=BN=256, BK=64, 8 waves (2M x 4N), 512 threads, 128 KiB LDS.
// NOTE: (512,2) is mandatory — acc[8][4]=128 AGPR + ~124 VGPR = 252 of the
// 256-reg unified cap at 2 waves/EU. (512,4) caps at 128 -> catastrophic spill (R5).
// R7: XCD-chunk swizzle on block decode (T1) — consecutive LOGICAL blocks share
// the A panel; chunking keeps them on one XCD's L2 (scores FETCH was 3x inputs).
// MODE 0: proj   -> bf16 C row-major, grid (nx, ny, z), plane nx*ny % 8 == 0
// MODE 1: scores -> bf16*scale into PACKED-TRI (128-blocks), grid (136, 1, nb)
template <int MODE>
__global__ __launch_bounds__(512, 2) void gemm8(const unsigned short* __restrict__ A, int lda,
                                                const unsigned short* __restrict__ B, int ldb,
                                                void* __restrict__ Cv, int ldc, int K, float scale,
                                                long long sA, long long sB, long long sC) {
  int by, bx;
  if constexpr (MODE == 1) {
    int b = xcd_chunk((int)blockIdx.x, 136);  // logical tri order, XCD-chunked
    by = (int)((__fsqrt_rn(8.f * b + 1.f) - 1.f) * 0.5f);
    while ((by + 1) * (by + 2) / 2 <= b) ++by;
    while (by * (by + 1) / 2 > b) --by;
    bx = b - by * (by + 1) / 2;
  } else {
    int u = (int)blockIdx.x + (int)gridDim.x * (int)blockIdx.y;
    int l = xcd_chunk(u, (int)(gridDim.x * gridDim.y));
    bx = l % (int)gridDim.x;  // logical: bx fastest -> consecutive share A row-panel
    by = l / (int)gridDim.x;
  }
  A += (long long)blockIdx.z * sA;
  B += (long long)blockIdx.z * sB;

  const int rowBase = by * 256;
  const int colBase = bx * 256;

  __shared__ unsigned short lds[65536];  // 128 KiB

  const int tid = threadIdx.x;
  const int wave = tid >> 6;
  const int lane = tid & 63;
  const int wr = wave >> 2;  // 0..1  (M half)
  const int wc = wave & 3;   // 0..3  (N quarter)

  // ---- staging source precompute (pre-swizzled global addresses) ----
  const int rS = (tid >> 2) & 127;                       // row within half-tile
  const int ceS = ((tid & 3) * 8) ^ ((rS & 8) << 1);     // logical k-el offset in 32-chunk
  const unsigned short* sAp[2][2];
  const unsigned short* sBp[2][2];
#pragma unroll
  for (int h = 0; h < 2; ++h)
#pragma unroll
    for (int c = 0; c < 2; ++c) {
      sAp[h][c] = A + (size_t)(rowBase + h * 128 + rS) * lda + c * 32 + ceS;
      sBp[h][c] = B + (size_t)(colBase + h * 128 + rS) * ldb + c * 32 + ceS;
    }
  const int nT = K >> 6;  // 64-el k-tiles
  const int nIter = nT >> 1;

  // ---- LDS read bases (swizzled) ----
  const int laneRow = lane & 15;
  const int csw = ((lane >> 4) * 8) ^ ((laneRow & 8) << 1);
  const int aBase = wr * 8192 + laneRow * 32 + csw;
  const int bBase = 16384 + (wc >> 1) * 8192 + ((wc & 1) * 64 + laneRow) * 32 + csw;

  f32x4 acc[8][4];
#pragma unroll
  for (int i = 0; i < 8; ++i)
#pragma unroll
    for (int j = 0; j < 4; ++j) {
      f32x4 z = {0.f, 0.f, 0.f, 0.f};
      acc[i][j] = z;
    }
  bf16x8 af[4][2];      // current qm: 4 M-frags x 2 k-slices
  bf16x8 bq[2][2][2];   // both qn: [qn][j][ks]

  auto STAGE_A = [&](int h, int tau, int bufsel) {
    if (tau < nT) {
      unsigned short* d = &lds[bufsel * 32768 + h * 8192 + wave * 512];
      load16_to_lds(sAp[h][0] + tau * 64, d);
      load16_to_lds(sAp[h][1] + tau * 64, d + 4096);
    }
  };
  auto STAGE_B = [&](int h, int tau, int bufsel) {
    if (tau < nT) {
      unsigned short* d = &lds[bufsel * 32768 + 16384 + h * 8192 + wave * 512];
      load16_to_lds(sBp[h][0] + tau * 64, d);
      load16_to_lds(sBp[h][1] + tau * 64, d + 4096);
    }
  };

#define LOAD_A(qm, CO)                                                                   \
  _Pragma("unroll") for (int i_ = 0; i_ < 4; ++i_)                                       \
  _Pragma("unroll") for (int ks_ = 0; ks_ < 2; ++ks_)                                    \
      af[i_][ks_] = *(const bf16x8*)&lds[(CO) + aBase + ks_ * 4096 + ((qm)*4 + i_) * 512];

#define LOAD_B(qn, CO)                                                                   \
  _Pragma("unroll") for (int j_ = 0; j_ < 2; ++j_)                                       \
  _Pragma("unroll") for (int ks_ = 0; ks_ < 2; ++ks_)                                    \
      bq[qn][j_][ks_] = *(const bf16x8*)&lds[(CO) + bBase + ks_ * 4096 + ((qn)*2 + j_) * 512];

#define MFMA_Q(qm, qn)                                                                   \
  {                                                                                      \
    __builtin_amdgcn_s_setprio(1);                                                       \
    _Pragma("unroll") for (int i_ = 0; i_ < 4; ++i_)                                     \
    _Pragma("unroll") for (int j_ = 0; j_ < 2; ++j_)                                     \
    _Pragma("unroll") for (int ks_ = 0; ks_ < 2; ++ks_)                                  \
        acc[(qm)*4 + i_][(qn)*2 + j_] = __builtin_amdgcn_mfma_f32_16x16x32_bf16(         \
            bq[qn][j_][ks_], af[i_][ks_], acc[(qm)*4 + i_][(qn)*2 + j_], 0, 0, 0);       \
    __builtin_amdgcn_s_setprio(0);                                                       \
  }

#define BAR() __builtin_amdgcn_s_barrier()
#define WLG0()                                             \
  {                                                        \
    asm volatile("s_waitcnt lgkmcnt(0)" ::: "memory");     \
    __builtin_amdgcn_sched_barrier(0);                     \
  }

  // ---- prologue: A(0),B(0) -> buf0; B(1) -> buf1 ----
  STAGE_A(0, 0, 0);
  STAGE_A(1, 0, 0);
  STAGE_B(0, 0, 0);
  STAGE_B(1, 0, 0);
  STAGE_B(0, 1, 1);
  STAGE_B(1, 1, 1);
  asm volatile("s_waitcnt vmcnt(4)" ::: "memory");  // tile 0 landed; B(1) may fly
  BAR();

  for (int it = 0; it < nIter; ++it) {
    const int ta = 2 * it + 1, tb = 2 * it + 2, tc = 2 * it + 3;
    const bool sb = tb < nT, sc = tc < nT;

    // ---- phase 1: tile t0 (buf0), quadrant (0,0) ----
    LOAD_A(0, 0);
    LOAD_B(0, 0);
    STAGE_A(0, ta, 1);
    BAR();
    WLG0();
    MFMA_Q(0, 0);
    BAR();
    // ---- phase 2: (0,1) ----
    LOAD_B(1, 0);
    STAGE_A(1, ta, 1);
    BAR();
    WLG0();
    MFMA_Q(0, 1);
    BAR();
    // ---- phase 3: (1,0) ----
    LOAD_A(1, 0);
    STAGE_B(0, tb, 0);
    BAR();
    WLG0();
    MFMA_Q(1, 0);
    BAR();
    // ---- phase 4: (1,1) + vmcnt ----
    STAGE_B(1, tb, 0);
    if (sb) { asm volatile("s_waitcnt vmcnt(4)" ::: "memory"); }
    else    { asm volatile("s_waitcnt vmcnt(0)" ::: "memory"); }
    BAR();
    MFMA_Q(1, 1);
    BAR();
    // ---- phase 5: tile t1 (buf1), quadrant (0,0) ----
    LOAD_A(0, 32768);
    LOAD_B(0, 32768);
    STAGE_A(0, tb, 0);
    BAR();
    WLG0();
    MFMA_Q(0, 0);
    BAR();
    // ---- phase 6: (0,1) ----
    LOAD_B(1, 32768);
    STAGE_A(1, tb, 0);
    BAR();
    WLG0();
    MFMA_Q(0, 1);
    BAR();
    // ---- phase 7: (1,0) ----
    LOAD_A(1, 32768);
    STAGE_B(0, tc, 1);
    BAR();
    WLG0();
    MFMA_Q(1, 0);
    BAR();
    // ---- phase 8: (1,1) + vmcnt ----
    STAGE_B(1, tc, 1);
    if (sc) { asm volatile("s_waitcnt vmcnt(4)" ::: "memory"); }
    else    { asm volatile("s_waitcnt vmcnt(0)" ::: "memory"); }
    BAR();
    MFMA_Q(1, 1);
    BAR();
  }

  // ---- epilogue: lane holds C[row=16fi+er][cols=16fj+ec..+3] per frag ----
  const int er = lane & 15;
  const int ec = (lane >> 4) * 4;
  if constexpr (MODE == 1) {
    const int rbB = 2 * by + wr;
    const int cbB = 2 * bx + (wc >> 1);
    if (cbB <= rbB) {  // skip upper quadrant of diagonal 256-tiles (not stored)
      unsigned short* C = (unsigned short*)Cv + (long long)blockIdx.z * sC +
                          (size_t)(rbB * (rbB + 1) / 2 + cbB) * TRI_BLK;
#pragma unroll
      for (int fi = 0; fi < 8; ++fi)
#pragma unroll
        for (int fj = 0; fj < 4; ++fj) {
          f32x4 a = acc[fi][fj];
          a[0] *= scale; a[1] *= scale; a[2] *= scale; a[3] *= scale;
          uint2 p;
          p.x = pack_bf16_trunc(a[0], a[1]);
          p.y = pack_bf16_trunc(a[2], a[3]);
          int row = fi * 16 + er;
          int col = (wc & 1) * 64 + fj * 16 + ec;
          *(uint2*)(C + row * 128 + col) = p;
        }
    }
  } else {
    unsigned short* C = (unsigned short*)Cv + (long long)blockIdx.z * sC;
#pragma unroll
    for (int fi = 0; fi < 8; ++fi)
#pragma unroll
      for (int fj = 0; fj < 4; ++fj) {
        uint2 p;
        p.x = pack_bf16_trunc(acc[fi][fj][0], acc[fi][fj][1]);
        p.y = pack_bf16_trunc(acc[fi][fj][2], acc[fi][fj][3]);
        size_t base = (size_t)(rowBase + wr * 128 + fi * 16 + er) * ldc +
                      (size_t)(colBase + wc * 64 + fj * 16 + ec);
        *(uint2*)(C + base) = p;
      }
  }
#undef LOAD_A
#undef LOAD_B
#undef MFMA_Q
#undef BAR
#undef WLG0
}

// ---------- PV: paired 128x256 tiles, 3-buffer deep pipeline ----------
// One block = TWO row-blocks (byDeep=31-p, byShallow=p): depth sum 66 k-tiles
// CONSTANT -> perfect balance, 256 equal blocks. 8 waves (2Mx4N), 64x64/wave.
// LDS 3 bufs x 24576 el (144 KiB); depth-2 pipeline, vmcnt(6); read-split P1/P2.
// R7: XCD-chunk swizzle — consecutive logical blocks (same p, 4 bx) share the
// P row-panels; chunking keeps them on one XCD.
__global__ __launch_bounds__(512, 2) void gemm_pv(const unsigned short* __restrict__ Sc,
                                                  const unsigned short* __restrict__ B, int ldb,
                                                  float* __restrict__ C, int ldc,
                                                  long long sA, long long sB, long long sC) {
  const int l = xcd_chunk((int)blockIdx.x, 64);
  const int p = l >> 2;   // 0..15 pair index
  const int bx = l & 3;
  const unsigned short* Ab = Sc + (long long)blockIdx.z * sA;
  B += (long long)blockIdx.z * sB;
  C += (long long)blockIdx.z * sC;
  const int colBase = bx * 256;

  __shared__ unsigned short lds[73728];  // 144 KiB (3 bufs x 48 KiB)

  const int tid = threadIdx.x;
  const int wave = tid >> 6;
  const int lane = tid & 63;
  const int wr = wave >> 2;  // 0..1 (M half of 128)
  const int wc = wave & 3;   // 0..3 (N quarter)

  const int rS = tid >> 2;                            // 0..127
  const int ceS = ((tid & 3) * 8) ^ ((rS & 8) << 1);  // swizzled k-el in 32-chunk
  const unsigned short* sBp[2][2];
#pragma unroll
  for (int h = 0; h < 2; ++h)
#pragma unroll
    for (int c = 0; c < 2; ++c)
      sBp[h][c] = B + (size_t)(colBase + h * 128 + rS) * ldb + c * 32 + ceS;

  const int laneRow = lane & 15;
  const int csw = ((lane >> 4) * 8) ^ ((laneRow & 8) << 1);
  const int aBase = wr * 2048 + laneRow * 32 + csw;
  const int bBase = 8192 + (wc >> 1) * 8192 + ((wc & 1) * 64 + laneRow) * 32 + csw;
  const int er = lane & 15;
  const int ec = (lane >> 4) * 4;

  bf16x8 af[4][2];
  bf16x8 bq[2][2][2];

#define LOAD_P1(CO)                                                                      \
  _Pragma("unroll") for (int i_ = 0; i_ < 4; ++i_)                                       \
  _Pragma("unroll") for (int ks_ = 0; ks_ < 2; ++ks_)                                    \
      af[i_][ks_] = *(const bf16x8*)&lds[(CO) + aBase + ks_ * 4096 + i_ * 512];          \
  _Pragma("unroll") for (int j_ = 0; j_ < 2; ++j_)                                       \
  _Pragma("unroll") for (int ks_ = 0; ks_ < 2; ++ks_)                                    \
      bq[0][j_][ks_] = *(const bf16x8*)&lds[(CO) + bBase + ks_ * 4096 + j_ * 512];

#define LOAD_P2(CO)                                                                      \
  _Pragma("unroll") for (int j_ = 0; j_ < 2; ++j_)                                       \
  _Pragma("unroll") for (int ks_ = 0; ks_ < 2; ++ks_)                                    \
      bq[1][j_][ks_] = *(const bf16x8*)&lds[(CO) + bBase + ks_ * 4096 + (2 + j_) * 512];

#define MFMA_Q(qn)                                                                       \
  {                                                                                      \
    __builtin_amdgcn_s_setprio(1);                                                       \
    _Pragma("unroll") for (int i_ = 0; i_ < 4; ++i_)                                     \
    _Pragma("unroll") for (int j_ = 0; j_ < 2; ++j_)                                     \
    _Pragma("unroll") for (int ks_ = 0; ks_ < 2; ++ks_)                                  \
        acc[i_][(qn)*2 + j_] = __builtin_amdgcn_mfma_f32_16x16x32_bf16(                  \
            bq[qn][j_][ks_], af[i_][ks_], acc[i_][(qn)*2 + j_], 0, 0, 0);                \
    __builtin_amdgcn_s_setprio(0);                                                       \
  }

#define BAR() __builtin_amdgcn_s_barrier()
#define WLG0()                                             \
  {                                                        \
    asm volatile("s_waitcnt lgkmcnt(0)" ::: "memory");     \
    __builtin_amdgcn_sched_barrier(0);                     \
  }

  for (int seg = 0; seg < 2; ++seg) {
    const int by = seg ? p : 31 - p;  // deep first, then shallow
    const int rowBase = by * 128;
    const int nT = 2 * (by + 1);  // 64-el k-tiles (even, >=2)
    const unsigned short* A = Ab + (size_t)(by * (by + 1) / 2) * TRI_BLK;
    const unsigned short* sAp0 = A + rS * 128 + ceS;
    const unsigned short* sAp1 = sAp0 + 32;

    auto STAGE_A = [&](int tau, int bufsel) {
      if (tau < nT) {
        long long o = (long long)(tau >> 1) * TRI_BLK + (tau & 1) * 64;
        unsigned short* d = &lds[bufsel * 24576 + wave * 512];
        load16_to_lds(sAp0 + o, d);
        load16_to_lds(sAp1 + o, d + 4096);
      }
    };
    auto STAGE_B = [&](int h, int tau, int bufsel) {
      if (tau < nT) {
        unsigned short* d = &lds[bufsel * 24576 + 8192 + h * 8192 + wave * 512];
        load16_to_lds(sBp[h][0] + tau * 64, d);
        load16_to_lds(sBp[h][1] + tau * 64, d + 4096);
      }
    };

    f32x4 acc[4][4];
#pragma unroll
    for (int i = 0; i < 4; ++i)
#pragma unroll
      for (int j = 0; j < 4; ++j) {
        f32x4 z = {0.f, 0.f, 0.f, 0.f};
        acc[i][j] = z;
      }

    // prologue: tile0 -> buf0 (6 ops), tile1 -> buf1 (6 ops)
    STAGE_A(0, 0);
    STAGE_B(0, 0, 0);
    STAGE_B(1, 0, 0);
    STAGE_A(1, 1);
    STAGE_B(0, 1, 1);
    STAGE_B(1, 1, 1);
    asm volatile("s_waitcnt vmcnt(6)" ::: "memory");  // tile 0 landed; tile 1 may fly
    BAR();

    int bsel = 0;
    for (int t = 0; t < nT; ++t) {
      const int tn = t + 2;
      int bn = bsel + 2; if (bn >= 3) bn -= 3;
      const int CO = bsel * 24576;

      // ---- phase 1: af + bq[0] ds_reads (12); issue A(t+2); MFMA qn0 ----
      LOAD_P1(CO);
      STAGE_A(tn, bn);
      BAR();
      WLG0();
      MFMA_Q(0);
      BAR();
      // ---- phase 2: bq[1] ds_reads (4); issue B(t+2); counted vmcnt; MFMA qn1 ----
      LOAD_P2(CO);
      STAGE_B(0, tn, bn);
      STAGE_B(1, tn, bn);
      if (tn < nT) { asm volatile("s_waitcnt vmcnt(6)" ::: "memory"); }
      else         { asm volatile("s_waitcnt vmcnt(0)" ::: "memory"); }
      BAR();
      WLG0();
      MFMA_Q(1);
      BAR();

      ++bsel; if (bsel >= 3) bsel = 0;
    }

    // ---- epilogue for this segment ----
#pragma unroll
    for (int fi = 0; fi < 4; ++fi)
#pragma unroll
      for (int fj = 0; fj < 4; ++fj) {
        size_t base = (size_t)(rowBase + wr * 64 + fi * 16 + er) * ldc +
                      (size_t)(colBase + wc * 64 + fj * 16 + ec);
        *(f32x4*)(C + base) = acc[fi][fj];
      }
  }
#undef LOAD_P1
#undef LOAD_P2
#undef MFMA_Q
#undef BAR
#undef WLG0
}

// ---------- in-place causal softmax over PACKED-TRI bf16 scores ----------
__global__ __launch_bounds__(256) void softmax_causal(unsigned short* __restrict__ Sc) {
  const int r = blockIdx.x;
  const int by = r >> 7;
  unsigned short* rowB = Sc + (size_t)blockIdx.y * PER_BATCH_EL +
                         (size_t)(by * (by + 1) / 2) * TRI_BLK + (size_t)(r & 127) * 128;
  const int ncols = (by + 1) << 7;  // multiple of 128
  const int tid = threadIdx.x;
  const int nIt = (ncols + 2047) >> 11;  // ceil(ncols / (256*8)) <= 2

  float v[16];
#pragma unroll
  for (int e = 0; e < 16; ++e) v[e] = -1e30f;
  float m = -1e30f;
#pragma unroll 2
  for (int it = 0; it < nIt; ++it) {
    int j0 = (it << 11) + tid * 8;  // 8 | 128 -> chunk stays in one segment
    if (j0 < ncols) {
      uint4 u = *(const uint4*)(rowB + ((j0 >> 7) << 14) + (j0 & 127));
      const unsigned short* us = (const unsigned short*)&u;
#pragma unroll
      for (int e = 0; e < 8; ++e) {
        float x = bf2f(us[e]);
        x = (j0 + e <= r) ? x : -1e30f;
        v[it * 8 + e] = x;
        m = fmaxf(m, x);
      }
    }
  }
  __shared__ float red[4];
  for (int off = 32; off; off >>= 1) m = fmaxf(m, __shfl_xor(m, off, 64));
  if ((tid & 63) == 0) red[tid >> 6] = m;
  __syncthreads();
  m = fmaxf(fmaxf(red[0], red[1]), fmaxf(red[2], red[3]));
  __syncthreads();

  float s = 0.f;
#pragma unroll
  for (int e = 0; e < 16; ++e) {
    float x = v[e];
    float ex = (x > -1e29f) ? __expf(x - m) : 0.f;
    v[e] = ex;
    s += ex;
  }
  for (int off = 32; off; off >>= 1) s += __shfl_xor(s, off, 64);
  if ((tid & 63) == 0) red[tid >> 6] = s;
  __syncthreads();
  s = red[0] + red[1] + red[2] + red[3];
  float inv = 1.f / s;

#pragma unroll 2
  for (int it = 0; it < nIt; ++it) {
    int j0 = (it << 11) + tid * 8;
    if (j0 < ncols) {
      uint4 o;
      unsigned int* po = (unsigned int*)&o;
#pragma unroll
      for (int e = 0; e < 4; ++e)
        po[e] = pack_bf16_trunc(v[it * 8 + 2 * e] * inv, v[it * 8 + 2 * e + 1] * inv);
      *(uint4*)(rowB + ((j0 >> 7) << 14) + (j0 & 127)) = o;
    }
  }
}

// ---------- launch ----------
extern "C" void kernel_launch(void* const* d_in, const int* in_sizes, int n_in,
                              void* d_out, int out_size, void* d_ws, size_t ws_size,
                              hipStream_t stream) {
  const float* X  = (const float*)d_in[0];
  const float* Wq = (const float*)d_in[1];
  const float* Wk = (const float*)d_in[2];
  const float* Wv = (const float*)d_in[3];
  float* out = (float*)d_out;

  const int Bsz = 4, S = 4096, D = 1024;
  const long long MD = (long long)Bsz * S;  // 16384 total rows
  const long long elBig = MD * D;           // 16,777,216

  // ws layout (bf16 el): Wb[3DD] Qb[elBig] Kb[elBig] Vt[elBig] Xb[elBig]...
  // Sc ALIASES Xb (Xb dead after projections; stream order makes reuse safe).
  unsigned short* Wb = (unsigned short*)d_ws;
  unsigned short* Qb = Wb + 3LL * D * D;
  unsigned short* Kb = Qb + elBig;
  unsigned short* Vt = Kb + elBig;
  unsigned short* Xb = Vt + elBig;
  unsigned short* Sc = Xb;  // packed-tri, PER_BATCH_EL per batch

  const long long offXb = 3LL * D * D + 3LL * elBig;
  auto needB = [&](int nb) {
    long long tail = (long long)nb * PER_BATCH_EL;
    if (tail < elBig) tail = elBig;
    return (size_t)((offXb + tail) * 2);
  };
  int nb = 1;
  if (ws_size >= needB(4)) nb = 4;        // 176.2 MB
  else if (ws_size >= needB(2)) nb = 2;   // 141.6 MB

  // 1) fused casts: X + Wq + Wk + Wv in one dispatch
  const int n4x = (int)(elBig / 4);          // 4,194,304
  const int n4w = D * D / 4;                 // 262,144 (pow2)
  const int n4tot = n4x + 3 * n4w;           // 4,980,736 = 19456 * 256
  cast_all<<<dim3((unsigned)(n4tot / 256)), 256, 0, stream>>>(X, Wq, Wk, Wv, Xb, Wb, n4x, n4w);

  // 2) Q,K projections: C[s][e] = X[s,:].W[e,:]  (z picks Wq/Wk -> Qb/Kb)
  gemm8<0><<<dim3(D / 256, (unsigned)(MD / 256), 2), 512, 0, stream>>>(
      Xb, D, Wb, D, (void*)Qb, D, D, 1.f, 0LL, (long long)D * D, elBig);
  // 3) V produced transposed: Vt[e][s] = Wv[e,:].X[s,:]
  gemm8<0><<<dim3((unsigned)(MD / 256), D / 256, 1), 512, 0, stream>>>(
      Wb + 2LL * D * D, D, Xb, D, (void*)Vt, (int)MD, D, 1.f, 0LL, 0LL, 0LL);

  // 4) per-batch-group: scores(packed tri) -> softmax -> PV (paired 128-row tiles)
  const float sscale = 1.0f / 32.0f;  // 1/sqrt(1024)
  for (int b0 = 0; b0 < Bsz; b0 += nb) {
    gemm8<1><<<dim3(136, 1, nb), 512, 0, stream>>>(
        Qb + (long long)b0 * S * D, D, Kb + (long long)b0 * S * D, D, (void*)Sc, 0, D, sscale,
        (long long)S * D, (long long)S * D, (long long)PER_BATCH_EL);
    softmax_causal<<<dim3(S, nb), 256, 0, stream>>>(Sc);
    gemm_pv<<<dim3(64, 1, nb), 512, 0, stream>>>(
        Sc, Vt + (long long)b0 * S, (int)MD, out + (long long)b0 * S * D, D,
        (long long)PER_BATCH_EL, (long long)S, (long long)S * D);
  }
}